// Round 12
// baseline (6746.969 us; speedup 1.0000x reference)
//
#include <hip/hip_runtime.h>
#include <hip/hip_bf16.h>

#define N_TOT 3840
#define B_SZ  128
#define K_REC 1792
#define T_STEPS 200
#define NTILES 240
#define LDS_HALF 29696   // u16 per half-tile: 58 kc * 64 lanes * 8 elems
#define HWREG_XCC_ID_IMM 6164   // id=20, offset=0, size=4
#define RING 8
#define RH_SLOT 229376   // u16 per rh/rl slot: 128*1792
#define DS_SLOT 262144   // f32 per ds slot (A half at 0, B half at 131072)
#define ROOT_NT 239      // root block: PFC-VIP tile, lightest epilogue

typedef __attribute__((ext_vector_type(8))) short short8;
typedef __attribute__((ext_vector_type(4))) float f32x4;
typedef unsigned long long u64;

__device__ __forceinline__ unsigned short f2bf(float f) {
    __hip_bfloat16 h = __float2bfloat16(f);
    return *reinterpret_cast<unsigned short*>(&h);
}
__device__ __forceinline__ float bf2f(unsigned short u) {
    __hip_bfloat16 h = *reinterpret_cast<__hip_bfloat16*>(&u);
    return __bfloat162float(h);
}

// ---- prep: W_aug^T in MFMA-fragment order: [tile][kc][lane][e], hi/lo bf16 ----
__global__ void prep_w(const float* __restrict__ w_rec, const float* __restrict__ w_in,
                       const float* __restrict__ mask,
                       unsigned short* __restrict__ Wfh, unsigned short* __restrict__ Wfl) {
    int n = blockIdx.x * 256 + threadIdx.x;
    int k = blockIdx.y;
    if (n >= N_TOT) return;
    float v;
    if (k < K_REC) {
        int region = (k >= 896) ? 1 : 0;
        int kk = k - 896 * region;
        int i = 1920 * region + (kk < 512 ? kk : 1024 + kk);
        v = fabsf(w_rec[(size_t)i * N_TOT + n]) * mask[(size_t)i * N_TOT + n];
    } else {
        v = w_in[(size_t)(k - K_REC) * N_TOT + n];
    }
    unsigned short hb = f2bf(v);
    unsigned short lb = f2bf(v - bf2f(hb));
    int nt = n >> 4;
    int l  = ((k >> 3) & 3) * 16 + (n & 15);   // fragment lane
    int kc = k >> 5, e = k & 7;
    size_t off = ((size_t)(nt * 58 + kc) * 64 + l) * 8 + e;
    Wfh[off] = hb;
    Wfl[off] = lb;
}

// ---- prep: x -> bf16 hi/lo ----
__global__ void prep_x(const float* __restrict__ x,
                       unsigned short* __restrict__ xh, unsigned short* __restrict__ xl) {
    int i = blockIdx.x * 256 + threadIdx.x;
    if (i >= T_STEPS * B_SZ * 64) return;
    float f = x[i];
    unsigned short hb = f2bf(f);
    xh[i] = hb;
    xl[i] = f2bf(f - bf2f(hb));
}

// ---- init ring slot 0 from h0 ----
__global__ void init_state(const float* __restrict__ h0,
                           unsigned short* __restrict__ rhR, unsigned short* __restrict__ rlR,
                           float* __restrict__ dsR) {
    int n = blockIdx.x * 256 + threadIdx.x;
    int b = blockIdx.y;
    if (n >= N_TOT) return;
    float hv = h0[(size_t)b * N_TOT + n];
    int region = (n >= 1920) ? 1 : 0;
    int nn = n - 1920 * region;
    bool dend = (nn >= 512 && nn < 1536);
    float r = dend ? tanhf(hv) : fmaxf(hv, 0.f);
    if (!dend) {
        int kc = 896 * region + (nn < 512 ? nn : nn - 1024);
        unsigned short hb = f2bf(r);
        rhR[b * K_REC + kc] = hb;
        rlR[b * K_REC + kc] = f2bf(r - bf2f(hb));
    } else {
        int d = nn - 512;
        int br = d >> 9;
        int c = region * 512 + (d & 511);
        dsR[br * 131072 + b * 1024 + c] = r;
    }
}

__global__ void zero_bar(int* __restrict__ bar) {
    for (int i = threadIdx.x; i < 8448; i += 1024) bar[i] = 0;
}

// ---- final readout reduction: out[t][b][o] = sum over 32 col-tile partials ----
__global__ void reduce_out(const float* __restrict__ part, float* __restrict__ out) {
    int t = blockIdx.x;
    for (int j = threadIdx.x; j < 1280; j += 256) {
        float s = 0.f;
        #pragma unroll
        for (int q = 0; q < 32; ++q) s += part[(size_t)t * 40960 + q * 1280 + j];
        out[(size_t)t * 1280 + j] = s;
    }
}

// bar ints: [nt*16] 240 arrive slots (own line each) | [4096+nt*16] 240 release slots
//           [8192+x] 8 leader claims | [8256+x*16] 8 xcd inv flags
// ---- persistent kernel: W in LDS, h in regs, sc1 stores, plain cached A-loads,
//      depth-8 ring + inv/8 steps, RMW-FREE lane-parallel sweep barrier ----
__global__ void __launch_bounds__(1024, 4)
rnn_persist(const unsigned short* __restrict__ Wfh, const unsigned short* __restrict__ Wfl,
            unsigned short* __restrict__ rhR, unsigned short* __restrict__ rlR,
            float* __restrict__ dsR,
            const unsigned short* __restrict__ xh, const unsigned short* __restrict__ xl,
            const float* __restrict__ noise, const float* __restrict__ bias,
            const float* __restrict__ w_out, const float* __restrict__ h0,
            float* __restrict__ part, int* __restrict__ bar) {
    __shared__ unsigned short Wh_s[LDS_HALF];
    __shared__ unsigned short Wl_s[LDS_HALF];
    __shared__ f32x4 red_s[8 * 64];
    __shared__ int xcc_s, lead_s;

    const int nt   = blockIdx.x;          // col tile 0..239
    const int tid  = threadIdx.x;
    const int lane = tid & 63;
    const int wv   = tid >> 6;            // 0..15
    const int m    = wv & 7;              // m-tile (rows m*16..+15)
    const int kh   = wv >> 3;             // k-half 0/1
    const int l15  = lane & 15, g = lane >> 4;

    // XCD team registration: leader = first block to claim its XCD (one-time)
    if (tid == 0) {
        int xcc = __builtin_amdgcn_s_getreg(HWREG_XCC_ID_IMM) & 7;
        xcc_s = xcc;
        lead_s = (__hip_atomic_fetch_add(&bar[8192 + xcc], 1,
                                         __ATOMIC_RELAXED, __HIP_MEMORY_SCOPE_AGENT) == 0);
    }

    // one-time: W tile (hi+lo, fragment order) -> LDS
    {
        const uint4* s0 = (const uint4*)(Wfh + (size_t)nt * LDS_HALF);
        const uint4* s1 = (const uint4*)(Wfl + (size_t)nt * LDS_HALF);
        uint4* d0 = (uint4*)Wh_s;
        uint4* d1 = (uint4*)Wl_s;
        for (int i = tid; i < LDS_HALF / 8; i += 1024) { d0[i] = s0[i]; d1[i] = s1[i]; }
    }
    __syncthreads();
    const int  xcc    = xcc_s;
    const bool leader = (lead_s != 0);

    // per-block column facts (uniform per block)
    const int n      = nt * 16 + l15;
    const int region = (n >= 1920) ? 1 : 0;
    const int nn     = n - 1920 * region;
    const bool es    = (nn < 512);
    const bool dend  = (nn >= 512 && nn < 1536);
    const int kcol   = 896 * region + (nn < 512 ? nn : nn - 1024);
    const int dd     = nn - 512;
    const int dbr    = (dd >> 9) & 1;
    const int dcol   = region * 512 + (dd & 511);
    const int esc    = region * 512 + nn;
    const float bias_v = bias[n];
    const bool is_read = (!region) && es;
    float wo[10];
    #pragma unroll
    for (int o = 0; o < 10; ++o) wo[o] = is_read ? w_out[n * 10 + o] : 0.f;
    const float nsc = sqrtf(0.4f) * 0.01f;

    const int bA    = m * 16 + l15;       // A-fragment row
    const int kbase = kh * 28;            // this wave's kc range start

    // h block-private in registers for all 200 steps (kh0 waves), from h0 input
    float hreg[4];
    if (!kh) {
        #pragma unroll
        for (int i = 0; i < 4; ++i)
            hreg[i] = h0[(size_t)(m * 16 + g * 4 + i) * N_TOT + n];
    }

    // prologue prefetch for t=0 (pure inputs)
    float nz[4];
    short8 xvh[2], xvl[2];
    if (!kh) {
        #pragma unroll
        for (int i = 0; i < 4; ++i)
            nz[i] = noise[(size_t)(m * 16 + g * 4 + i) * N_TOT + n];
    } else {
        const unsigned short* xH = xh + (size_t)bA * 64 + g * 8;
        const unsigned short* xL = xl + (size_t)bA * 64 + g * 8;
        #pragma unroll
        for (int c = 0; c < 2; ++c) {
            xvh[c] = *reinterpret_cast<const short8*>(xH + c * 32);
            xvl[c] = *reinterpret_cast<const short8*>(xL + c * 32);
        }
    }

    for (int t = 0; t < T_STEPS; ++t) {
        const int sc = t & (RING - 1);            // slot consumed this step
        const int sn = (t + 1) & (RING - 1);      // slot produced this step
        const unsigned short* rhc = rhR + (size_t)sc * RH_SLOT;
        const unsigned short* rlc = rlR + (size_t)sc * RH_SLOT;
        unsigned short* rhn = rhR + (size_t)sn * RH_SLOT;
        unsigned short* rln = rlR + (size_t)sn * RH_SLOT;
        const float* dsAc = dsR + (size_t)sc * DS_SLOT;
        const float* dsBc = dsAc + 131072;
        float* dsAn = dsR + (size_t)sn * DS_SLOT;
        float* dsBn = dsAn + 131072;

        // cross-block epilogue inputs: plain cached loads (ring+inv guarantee freshness)
        float dsv0[4], dsv1[4];
        if (!kh) {
            #pragma unroll
            for (int i = 0; i < 4; ++i) {
                int b = m * 16 + g * 4 + i;
                dsv0[i] = es ? dsAc[b * 1024 + esc] : 0.f;
                dsv1[i] = es ? dsBc[b * 1024 + esc] : 0.f;
            }
        }

        const unsigned short* aH = rhc + (size_t)bA * K_REC + kbase * 32 + g * 8;
        const unsigned short* aL = rlc + (size_t)bA * K_REC + kbase * 32 + g * 8;

        // 3-deep prefetch ring, plain cached loads (r7/r11-identical GEMM)
        f32x4 acc = {0.f, 0.f, 0.f, 0.f};
        short8 pah[3], pal[3];
        #pragma unroll
        for (int j = 0; j < 3; ++j) {
            pah[j] = *reinterpret_cast<const short8*>(aH + j * 32);
            pal[j] = *reinterpret_cast<const short8*>(aL + j * 32);
        }
        #pragma unroll
        for (int kc = 0; kc < 28; ++kc) {
            short8 cah = pah[kc % 3], cal = pal[kc % 3];
            if (kc < 25) {
                pah[kc % 3] = *reinterpret_cast<const short8*>(aH + (kc + 3) * 32);
                pal[kc % 3] = *reinterpret_cast<const short8*>(aL + (kc + 3) * 32);
            }
            int ka = kbase + kc;
            short8 bvh = *reinterpret_cast<const short8*>(Wh_s + (ka * 64 + lane) * 8);
            short8 bvl = *reinterpret_cast<const short8*>(Wl_s + (ka * 64 + lane) * 8);
            acc = __builtin_amdgcn_mfma_f32_16x16x32_bf16(cah, bvh, acc, 0, 0, 0);
            acc = __builtin_amdgcn_mfma_f32_16x16x32_bf16(cah, bvl, acc, 0, 0, 0);
            acc = __builtin_amdgcn_mfma_f32_16x16x32_bf16(cal, bvh, acc, 0, 0, 0);
        }
        if (kh) {
            #pragma unroll
            for (int c = 0; c < 2; ++c) {
                short8 bvh = *reinterpret_cast<const short8*>(Wh_s + ((56 + c) * 64 + lane) * 8);
                short8 bvl = *reinterpret_cast<const short8*>(Wl_s + ((56 + c) * 64 + lane) * 8);
                acc = __builtin_amdgcn_mfma_f32_16x16x32_bf16(xvh[c], bvh, acc, 0, 0, 0);
                acc = __builtin_amdgcn_mfma_f32_16x16x32_bf16(xvh[c], bvl, acc, 0, 0, 0);
                acc = __builtin_amdgcn_mfma_f32_16x16x32_bf16(xvl[c], bvh, acc, 0, 0, 0);
            }
            red_s[m * 64 + lane] = acc;    // publish partial
        }
        __syncthreads();

        if (!kh) {
            f32x4 o4 = red_s[m * 64 + lane];
            acc[0] += o4[0]; acc[1] += o4[1]; acc[2] += o4[2]; acc[3] += o4[3];
            #pragma unroll
            for (int i = 0; i < 4; ++i) {
                int b = m * 16 + g * 4 + i;
                float tot = acc[i] + bias_v;
                if (es) tot += dsv0[i] + dsv1[i];
                float hn = 0.8f * hreg[i] + 0.2f * tot + nsc * nz[i];
                hreg[i] = hn;
                float r = dend ? tanhf(hn) : fmaxf(hn, 0.f);
                if (!dend) {
                    // adjacent lanes own adjacent kcol: pair into one u32 sc1 store
                    unsigned int hv32 = f2bf(r);
                    unsigned int lv32 = f2bf(r - bf2f((unsigned short)hv32));
                    unsigned int hp = (unsigned int)__shfl_xor((int)hv32, 1);
                    unsigned int lp = (unsigned int)__shfl_xor((int)lv32, 1);
                    if (!(l15 & 1)) {
                        __hip_atomic_store((unsigned int*)(rhn + b * K_REC + kcol),
                                           hv32 | (hp << 16),
                                           __ATOMIC_RELAXED, __HIP_MEMORY_SCOPE_AGENT);
                        __hip_atomic_store((unsigned int*)(rln + b * K_REC + kcol),
                                           lv32 | (lp << 16),
                                           __ATOMIC_RELAXED, __HIP_MEMORY_SCOPE_AGENT);
                    }
                } else {
                    // adjacent lanes own adjacent dcol: pair into one u64 sc1 store
                    unsigned int rb = __float_as_uint(r);
                    unsigned int rp = (unsigned int)__shfl_xor((int)rb, 1);
                    if (!(l15 & 1)) {
                        float* dst = (dbr ? dsBn : dsAn) + b * 1024 + dcol;
                        u64 w = (u64)rb | ((u64)rp << 32);
                        __hip_atomic_store((u64*)dst, w,
                                           __ATOMIC_RELAXED, __HIP_MEMORY_SCOPE_AGENT);
                    }
                }
                if (is_read) {
                    #pragma unroll
                    for (int o = 0; o < 10; ++o) {
                        float pp = r * wo[o];
                        pp += __shfl_xor(pp, 1);
                        pp += __shfl_xor(pp, 2);
                        pp += __shfl_xor(pp, 4);
                        pp += __shfl_xor(pp, 8);
                        if (l15 == 0)
                            __hip_atomic_store(&part[(size_t)t * 40960 + nt * 1280 + b * 10 + o],
                                               pp, __ATOMIC_RELAXED, __HIP_MEMORY_SCOPE_AGENT);
                    }
                }
            }
        }

        // prefetch PURE INPUTS for t+1 before the barrier (latency hides under it)
        if (t != T_STEPS - 1) {
            const int e1 = t + 1;
            if (!kh) {
                const float* noise_nx = noise + (size_t)(t + 1) * B_SZ * N_TOT;
                #pragma unroll
                for (int i = 0; i < 4; ++i)
                    nz[i] = noise_nx[(size_t)(m * 16 + g * 4 + i) * N_TOT + n];
            } else {
                const unsigned short* xH = xh + ((size_t)(t + 1) * B_SZ + bA) * 64 + g * 8;
                const unsigned short* xL = xl + ((size_t)(t + 1) * B_SZ + bA) * 64 + g * 8;
                #pragma unroll
                for (int c = 0; c < 2; ++c) {
                    xvh[c] = *reinterpret_cast<const short8*>(xH + c * 32);
                    xvl[c] = *reinterpret_cast<const short8*>(xL + c * 32);
                }
            }

            // ---- RMW-free sweep barrier ----
            __syncthreads();    // all waves' sc1 stores drained (vmcnt 0) before arrive
            // arrive: one store to this block's own line
            if (tid == 0)
                __hip_atomic_store(&bar[nt * 16], e1,
                                   __ATOMIC_RELAXED, __HIP_MEMORY_SCOPE_AGENT);
            // root sweep + release broadcast (wave 0 of ROOT block, lane-parallel)
            if (nt == ROOT_NT && wv == 0) {
                for (;;) {
                    bool ok = true;
                    #pragma unroll
                    for (int j = 0; j < 4; ++j) {
                        int idx = j * 64 + lane;
                        if (idx < NTILES) {
                            int v = __hip_atomic_load(&bar[idx * 16], __ATOMIC_RELAXED,
                                                      __HIP_MEMORY_SCOPE_AGENT);
                            ok = ok && (v >= e1);
                        }
                    }
                    if (__all(ok)) break;
                    __builtin_amdgcn_s_sleep(1);
                }
                #pragma unroll
                for (int j = 0; j < 4; ++j) {
                    int idx = j * 64 + lane;
                    if (idx < NTILES)
                        __hip_atomic_store(&bar[4096 + idx * 16], e1,
                                           __ATOMIC_RELAXED, __HIP_MEMORY_SCOPE_AGENT);
                }
            }
            // wake: poll own release line (zero contention, single hop)
            if (tid == 0) {
                while (__hip_atomic_load(&bar[4096 + nt * 16], __ATOMIC_RELAXED,
                                         __HIP_MEMORY_SCOPE_AGENT) < e1)
                    __builtin_amdgcn_s_sleep(1);
                // inv step (1 in 8): leader invalidates XCD L2 once, members wait for it
                if ((t & (RING - 1)) == RING - 1) {
                    if (leader) {
                        __builtin_amdgcn_fence(__ATOMIC_ACQUIRE, "agent");  // the one inv
                        __hip_atomic_store(&bar[8256 + xcc * 16], e1,
                                           __ATOMIC_RELAXED, __HIP_MEMORY_SCOPE_AGENT);
                    }
                    while (__hip_atomic_load(&bar[8256 + xcc * 16], __ATOMIC_RELAXED,
                                             __HIP_MEMORY_SCOPE_AGENT) < e1)
                        __builtin_amdgcn_s_sleep(1);
                }
                asm volatile("" ::: "memory");
            }
            __syncthreads();
        }
    }
}

extern "C" void kernel_launch(void* const* d_in, const int* in_sizes, int n_in,
                              void* d_out, int out_size, void* d_ws, size_t ws_size,
                              hipStream_t stream) {
    const float* x     = (const float*)d_in[0];
    const float* noise = (const float*)d_in[1];
    const float* w_rec = (const float*)d_in[2];
    const float* w_in  = (const float*)d_in[3];
    const float* w_out = (const float*)d_in[4];
    const float* bias  = (const float*)d_in[5];
    const float* h0    = (const float*)d_in[6];
    const float* mask  = (const float*)d_in[7];
    float* out = (float*)d_out;

    char* ws = (char*)d_ws;
    unsigned short* Wfh = (unsigned short*)(ws + 0);
    unsigned short* Wfl = (unsigned short*)(ws + 14254080);
    unsigned short* rhR = (unsigned short*)(ws + 28508160);   // 8 x 458752 B
    unsigned short* rlR = (unsigned short*)(ws + 32178176);   // 8 x 458752 B
    float* dsR = (float*)(ws + 35848192);                     // 8 x 1048576 B
    unsigned short* xh = (unsigned short*)(ws + 44236800);
    unsigned short* xl = (unsigned short*)(ws + 47513600);
    int*   bar  = (int*)(ws + 50790400);                      // 33792 B
    float* part = (float*)(ws + 50824192);                    // 32.77 MB

    hipLaunchKernelGGL(prep_w, dim3(15, 1856), dim3(256), 0, stream, w_rec, w_in, mask, Wfh, Wfl);
    hipLaunchKernelGGL(prep_x, dim3(6400), dim3(256), 0, stream, x, xh, xl);
    hipLaunchKernelGGL(init_state, dim3(15, B_SZ), dim3(256), 0, stream, h0, rhR, rlR, dsR);
    hipLaunchKernelGGL(zero_bar, dim3(1), dim3(1024), 0, stream, bar);

    void* params[] = {
        (void*)&Wfh, (void*)&Wfl, (void*)&rhR, (void*)&rlR, (void*)&dsR,
        (void*)&xh, (void*)&xl, (void*)&noise, (void*)&bias, (void*)&w_out,
        (void*)&h0, (void*)&part, (void*)&bar
    };
    hipLaunchCooperativeKernel(rnn_persist, dim3(NTILES), dim3(1024), params, 0, stream);

    hipLaunchKernelGGL(reduce_out, dim3(T_STEPS), dim3(256), 0, stream, part, out);
}

// Round 13
// 6665.759 us; speedup vs baseline: 1.0122x; 1.0122x over previous
//
#include <hip/hip_runtime.h>
#include <hip/hip_bf16.h>

#define N_TOT 3840
#define B_SZ  128
#define K_REC 1792
#define T_STEPS 200
#define NTILES 240
#define LDS_HALF 29696   // u16 per half-tile: 58 kc * 64 lanes * 8 elems
#define HWREG_XCC_ID_IMM 6164   // id=20, offset=0, size=4
#define RING 8
#define RST_SLOT 458752  // u16 per rSt slot: 128 rows * 112 kblocks * 32
#define DS_SLOT 262144   // f32 per ds slot (A half at 0, B half at 131072)
#define ROOT_NT 239

typedef __attribute__((ext_vector_type(8))) short short8;
typedef __attribute__((ext_vector_type(4))) float f32x4;
typedef unsigned long long u64;

__device__ __forceinline__ unsigned short f2bf(float f) {
    __hip_bfloat16 h = __float2bfloat16(f);
    return *reinterpret_cast<unsigned short*>(&h);
}
__device__ __forceinline__ float bf2f(unsigned short u) {
    __hip_bfloat16 h = *reinterpret_cast<__hip_bfloat16*>(&u);
    return __bfloat162float(h);
}
__device__ __forceinline__ void st16_sc1(void* p, short8 v) {
    asm volatile("global_store_dwordx4 %0, %1, off sc1" :: "v"(p), "v"(v) : "memory");
}
__device__ __forceinline__ void st16f_sc1(void* p, f32x4 v) {
    asm volatile("global_store_dwordx4 %0, %1, off sc1" :: "v"(p), "v"(v) : "memory");
}

// ---- prep: W_aug^T in MFMA-fragment order: [tile][kc][lane][e], hi/lo bf16 ----
__global__ void prep_w(const float* __restrict__ w_rec, const float* __restrict__ w_in,
                       const float* __restrict__ mask,
                       unsigned short* __restrict__ Wfh, unsigned short* __restrict__ Wfl) {
    int n = blockIdx.x * 256 + threadIdx.x;
    int k = blockIdx.y;
    if (n >= N_TOT) return;
    float v;
    if (k < K_REC) {
        int region = (k >= 896) ? 1 : 0;
        int kk = k - 896 * region;
        int i = 1920 * region + (kk < 512 ? kk : 1024 + kk);
        v = fabsf(w_rec[(size_t)i * N_TOT + n]) * mask[(size_t)i * N_TOT + n];
    } else {
        v = w_in[(size_t)(k - K_REC) * N_TOT + n];
    }
    unsigned short hb = f2bf(v);
    unsigned short lb = f2bf(v - bf2f(hb));
    int nt = n >> 4;
    int l  = ((k >> 3) & 3) * 16 + (n & 15);   // fragment lane
    int kc = k >> 5, e = k & 7;
    size_t off = ((size_t)(nt * 58 + kc) * 64 + l) * 8 + e;
    Wfh[off] = hb;
    Wfl[off] = lb;
}

// ---- prep: x -> bf16 hi/lo ----
__global__ void prep_x(const float* __restrict__ x,
                       unsigned short* __restrict__ xh, unsigned short* __restrict__ xl) {
    int i = blockIdx.x * 256 + threadIdx.x;
    if (i >= T_STEPS * B_SZ * 64) return;
    float f = x[i];
    unsigned short hb = f2bf(f);
    xh[i] = hb;
    xl[i] = f2bf(f - bf2f(hb));
}

// ---- init ring slot 0 from h0: rSt layout [b][112][hi16|lo16] ----
__global__ void init_state(const float* __restrict__ h0,
                           unsigned short* __restrict__ rSt, float* __restrict__ dsR) {
    int n = blockIdx.x * 256 + threadIdx.x;
    int b = blockIdx.y;
    if (n >= N_TOT) return;
    float hv = h0[(size_t)b * N_TOT + n];
    int region = (n >= 1920) ? 1 : 0;
    int nn = n - 1920 * region;
    bool dend = (nn >= 512 && nn < 1536);
    float r = dend ? tanhf(hv) : fmaxf(hv, 0.f);
    if (!dend) {
        int kcol = 896 * region + (nn < 512 ? nn : nn - 1024);
        unsigned short hb = f2bf(r);
        size_t off = ((size_t)b * 112 + (kcol >> 4)) * 32 + (kcol & 15);
        rSt[off]      = hb;
        rSt[off + 16] = f2bf(r - bf2f(hb));
    } else {
        int d = nn - 512;
        int br = d >> 9;
        int c = region * 512 + (d & 511);
        dsR[br * 131072 + b * 1024 + c] = r;
    }
}

__global__ void zero_bar(int* __restrict__ bar) {
    for (int i = threadIdx.x; i < 8448; i += 1024) bar[i] = 0;
}

// ---- final readout reduction ----
__global__ void reduce_out(const float* __restrict__ part, float* __restrict__ out) {
    int t = blockIdx.x;
    for (int j = threadIdx.x; j < 1280; j += 256) {
        float s = 0.f;
        #pragma unroll
        for (int q = 0; q < 32; ++q) s += part[(size_t)t * 40960 + q * 1280 + j];
        out[(size_t)t * 1280 + j] = s;
    }
}

// bar ints: [nt*16] arrive | [4096+nt*16] release | [8192+x] claims | [8256+x*16] inv flags
__global__ void __launch_bounds__(1024, 4)
rnn_persist(const unsigned short* __restrict__ Wfh, const unsigned short* __restrict__ Wfl,
            unsigned short* __restrict__ rSt, float* __restrict__ dsR,
            const unsigned short* __restrict__ xh, const unsigned short* __restrict__ xl,
            const float* __restrict__ noise, const float* __restrict__ bias,
            const float* __restrict__ w_out, const float* __restrict__ h0,
            float* __restrict__ part, int* __restrict__ bar) {
    __shared__ unsigned short Wh_s[LDS_HALF];
    __shared__ unsigned short Wl_s[LDS_HALF];
    __shared__ f32x4 red_s[8 * 64];      // also per-wave 1KB transpose scratch
    __shared__ int xcc_s, lead_s;
    char* scratch = (char*)red_s;

    const int nt   = blockIdx.x;
    const int tid  = threadIdx.x;
    const int lane = tid & 63;
    const int wv   = tid >> 6;
    const int m    = wv & 7;
    const int kh   = wv >> 3;
    const int l15  = lane & 15, g = lane >> 4;

    if (tid == 0) {
        int xcc = __builtin_amdgcn_s_getreg(HWREG_XCC_ID_IMM) & 7;
        xcc_s = xcc;
        lead_s = (__hip_atomic_fetch_add(&bar[8192 + xcc], 1,
                                         __ATOMIC_RELAXED, __HIP_MEMORY_SCOPE_AGENT) == 0);
    }

    {   // one-time: W tile -> LDS
        const uint4* s0 = (const uint4*)(Wfh + (size_t)nt * LDS_HALF);
        const uint4* s1 = (const uint4*)(Wfl + (size_t)nt * LDS_HALF);
        uint4* d0 = (uint4*)Wh_s;
        uint4* d1 = (uint4*)Wl_s;
        for (int i = tid; i < LDS_HALF / 8; i += 1024) { d0[i] = s0[i]; d1[i] = s1[i]; }
    }
    __syncthreads();
    const int  xcc    = xcc_s;
    const bool leader = (lead_s != 0);

    const int n      = nt * 16 + l15;
    const int region = (n >= 1920) ? 1 : 0;
    const int nn     = n - 1920 * region;
    const bool es    = (nn < 512);
    const bool dend  = (nn >= 512 && nn < 1536);
    const int kcol   = 896 * region + (nn < 512 ? nn : nn - 1024);
    const int KB     = (kcol - l15) >> 4;            // block's kblock (somatic)
    const int dd     = nn - 512;
    const int dbr    = (dd >> 9) & 1;
    const int dcol   = region * 512 + (dd & 511);
    const int dcol0  = dcol - l15;                   // block's first ds col (dend)
    const int esc    = region * 512 + nn;
    const float bias_v = bias[n];
    const bool is_read = (!region) && es;
    float wo[10];
    #pragma unroll
    for (int o = 0; o < 10; ++o) wo[o] = is_read ? w_out[n * 10 + o] : 0.f;
    const float nsc = sqrtf(0.4f) * 0.01f;

    const int bA    = m * 16 + l15;
    const int kbase = kh * 28;
    const int gofs  = (g >> 1) * 32 + (g & 1) * 8;   // u16 offset within kblock pair

    float hreg[4];
    if (!kh) {
        #pragma unroll
        for (int i = 0; i < 4; ++i)
            hreg[i] = h0[(size_t)(m * 16 + g * 4 + i) * N_TOT + n];
    }

    float nz[4];
    short8 xvh[2], xvl[2];
    if (!kh) {
        #pragma unroll
        for (int i = 0; i < 4; ++i)
            nz[i] = noise[(size_t)(m * 16 + g * 4 + i) * N_TOT + n];
    } else {
        const unsigned short* xH = xh + (size_t)bA * 64 + g * 8;
        const unsigned short* xL = xl + (size_t)bA * 64 + g * 8;
        #pragma unroll
        for (int c = 0; c < 2; ++c) {
            xvh[c] = *reinterpret_cast<const short8*>(xH + c * 32);
            xvl[c] = *reinterpret_cast<const short8*>(xL + c * 32);
        }
    }

    for (int t = 0; t < T_STEPS; ++t) {
        const int sc = t & (RING - 1);
        const int sn = (t + 1) & (RING - 1);
        const unsigned short* rc = rSt + (size_t)sc * RST_SLOT;
        unsigned short* rn = rSt + (size_t)sn * RST_SLOT;
        const float* dsAc = dsR + (size_t)sc * DS_SLOT;
        const float* dsBc = dsAc + 131072;
        float* dsAn = dsR + (size_t)sn * DS_SLOT;
        float* dsBn = dsAn + 131072;

        float dsv0[4], dsv1[4];
        if (!kh) {
            #pragma unroll
            for (int i = 0; i < 4; ++i) {
                int b = m * 16 + g * 4 + i;
                dsv0[i] = es ? dsAc[b * 1024 + esc] : 0.f;
                dsv1[i] = es ? dsBc[b * 1024 + esc] : 0.f;
            }
        }

        // A-fragment base: hi at aB + kc*64, lo at +16 (same 64B line)
        const unsigned short* aB = rc + (size_t)bA * 3584 + (size_t)kbase * 64 + gofs;

        f32x4 acc = {0.f, 0.f, 0.f, 0.f};
        short8 pah[3], pal[3];
        #pragma unroll
        for (int j = 0; j < 3; ++j) {
            pah[j] = *reinterpret_cast<const short8*>(aB + j * 64);
            pal[j] = *reinterpret_cast<const short8*>(aB + j * 64 + 16);
        }
        #pragma unroll
        for (int kc = 0; kc < 28; ++kc) {
            short8 cah = pah[kc % 3], cal = pal[kc % 3];
            if (kc < 25) {
                pah[kc % 3] = *reinterpret_cast<const short8*>(aB + (kc + 3) * 64);
                pal[kc % 3] = *reinterpret_cast<const short8*>(aB + (kc + 3) * 64 + 16);
            }
            int ka = kbase + kc;
            short8 bvh = *reinterpret_cast<const short8*>(Wh_s + (ka * 64 + lane) * 8);
            short8 bvl = *reinterpret_cast<const short8*>(Wl_s + (ka * 64 + lane) * 8);
            acc = __builtin_amdgcn_mfma_f32_16x16x32_bf16(cah, bvh, acc, 0, 0, 0);
            acc = __builtin_amdgcn_mfma_f32_16x16x32_bf16(cah, bvl, acc, 0, 0, 0);
            acc = __builtin_amdgcn_mfma_f32_16x16x32_bf16(cal, bvh, acc, 0, 0, 0);
        }
        if (kh) {
            #pragma unroll
            for (int c = 0; c < 2; ++c) {
                short8 bvh = *reinterpret_cast<const short8*>(Wh_s + ((56 + c) * 64 + lane) * 8);
                short8 bvl = *reinterpret_cast<const short8*>(Wl_s + ((56 + c) * 64 + lane) * 8);
                acc = __builtin_amdgcn_mfma_f32_16x16x32_bf16(xvh[c], bvh, acc, 0, 0, 0);
                acc = __builtin_amdgcn_mfma_f32_16x16x32_bf16(xvh[c], bvl, acc, 0, 0, 0);
                acc = __builtin_amdgcn_mfma_f32_16x16x32_bf16(xvl[c], bvh, acc, 0, 0, 0);
            }
            red_s[m * 64 + lane] = acc;
        }
        __syncthreads();

        if (!kh) {
            f32x4 o4 = red_s[m * 64 + lane];   // read scratch BEFORE reuse
            acc[0] += o4[0]; acc[1] += o4[1]; acc[2] += o4[2]; acc[3] += o4[3];
            char* wreg = scratch + m * 1024;   // this wave's private 1KB
            unsigned short* hiT = (unsigned short*)wreg;        // [16row][16col]
            unsigned short* loT = hiT + 256;
            float*          fT  = (float*)wreg;                 // dend: [16row][16col]

            #pragma unroll
            for (int i = 0; i < 4; ++i) {
                float tot = acc[i] + bias_v;
                if (es) tot += dsv0[i] + dsv1[i];
                float hn = 0.8f * hreg[i] + 0.2f * tot + nsc * nz[i];
                hreg[i] = hn;
                float r = dend ? tanhf(hn) : fmaxf(hn, 0.f);
                int row = g * 4 + i;
                if (!dend) {
                    unsigned short hb = f2bf(r);
                    hiT[row * 16 + l15] = hb;
                    loT[row * 16 + l15] = f2bf(r - bf2f(hb));
                } else {
                    fT[row * 16 + l15] = r;
                }
                if (is_read) {
                    #pragma unroll
                    for (int o = 0; o < 10; ++o) {
                        float pp = r * wo[o];
                        pp += __shfl_xor(pp, 1);
                        pp += __shfl_xor(pp, 2);
                        pp += __shfl_xor(pp, 4);
                        pp += __shfl_xor(pp, 8);
                        int b = m * 16 + row;
                        if (l15 == 0)
                            __hip_atomic_store(&part[(size_t)t * 40960 + nt * 1280 + b * 10 + o],
                                               pp, __ATOMIC_RELAXED, __HIP_MEMORY_SCOPE_AGENT);
                    }
                }
            }
            // transpose-read + ONE coalesced 16B sc1 store per lane
            {
                int row = lane & 15, q = lane >> 4;
                int B = m * 16 + row;
                if (!dend) {
                    short8 v;
                    if (q < 2) v = *reinterpret_cast<short8*>(wreg + row * 32 + q * 16);
                    else       v = *reinterpret_cast<short8*>(wreg + 512 + row * 32 + (q - 2) * 16);
                    char* dst = (char*)rn + ((size_t)B * 112 + KB) * 64 + q * 16;
                    st16_sc1(dst, v);
                } else {
                    f32x4 v = *reinterpret_cast<f32x4*>(wreg + row * 64 + q * 16);
                    float* base = (dbr ? dsBn : dsAn) + B * 1024 + dcol0;
                    st16f_sc1((char*)base + q * 16, v);
                }
            }
        }

        if (t != T_STEPS - 1) {
            const int e1 = t + 1;
            if (!kh) {
                const float* noise_nx = noise + (size_t)(t + 1) * B_SZ * N_TOT;
                #pragma unroll
                for (int i = 0; i < 4; ++i)
                    nz[i] = noise_nx[(size_t)(m * 16 + g * 4 + i) * N_TOT + n];
            } else {
                const unsigned short* xH = xh + ((size_t)(t + 1) * B_SZ + bA) * 64 + g * 8;
                const unsigned short* xL = xl + ((size_t)(t + 1) * B_SZ + bA) * 64 + g * 8;
                #pragma unroll
                for (int c = 0; c < 2; ++c) {
                    xvh[c] = *reinterpret_cast<const short8*>(xH + c * 32);
                    xvl[c] = *reinterpret_cast<const short8*>(xL + c * 32);
                }
            }

            // ---- RMW-free sweep barrier (r12) ----
            __syncthreads();    // drains all sc1 stores (vmcnt 0) before arrive
            if (tid == 0)
                __hip_atomic_store(&bar[nt * 16], e1,
                                   __ATOMIC_RELAXED, __HIP_MEMORY_SCOPE_AGENT);
            if (nt == ROOT_NT && wv == 0) {
                for (;;) {
                    bool ok = true;
                    #pragma unroll
                    for (int j = 0; j < 4; ++j) {
                        int idx = j * 64 + lane;
                        if (idx < NTILES) {
                            int v = __hip_atomic_load(&bar[idx * 16], __ATOMIC_RELAXED,
                                                      __HIP_MEMORY_SCOPE_AGENT);
                            ok = ok && (v >= e1);
                        }
                    }
                    if (__all(ok)) break;
                    __builtin_amdgcn_s_sleep(1);
                }
                #pragma unroll
                for (int j = 0; j < 4; ++j) {
                    int idx = j * 64 + lane;
                    if (idx < NTILES)
                        __hip_atomic_store(&bar[4096 + idx * 16], e1,
                                           __ATOMIC_RELAXED, __HIP_MEMORY_SCOPE_AGENT);
                }
            }
            if (tid == 0) {
                while (__hip_atomic_load(&bar[4096 + nt * 16], __ATOMIC_RELAXED,
                                         __HIP_MEMORY_SCOPE_AGENT) < e1)
                    __builtin_amdgcn_s_sleep(1);
                if ((t & (RING - 1)) == RING - 1) {
                    if (leader) {
                        __builtin_amdgcn_fence(__ATOMIC_ACQUIRE, "agent");
                        __hip_atomic_store(&bar[8256 + xcc * 16], e1,
                                           __ATOMIC_RELAXED, __HIP_MEMORY_SCOPE_AGENT);
                    }
                    while (__hip_atomic_load(&bar[8256 + xcc * 16], __ATOMIC_RELAXED,
                                             __HIP_MEMORY_SCOPE_AGENT) < e1)
                        __builtin_amdgcn_s_sleep(1);
                }
                asm volatile("" ::: "memory");
            }
            __syncthreads();
        }
    }
}

extern "C" void kernel_launch(void* const* d_in, const int* in_sizes, int n_in,
                              void* d_out, int out_size, void* d_ws, size_t ws_size,
                              hipStream_t stream) {
    const float* x     = (const float*)d_in[0];
    const float* noise = (const float*)d_in[1];
    const float* w_rec = (const float*)d_in[2];
    const float* w_in  = (const float*)d_in[3];
    const float* w_out = (const float*)d_in[4];
    const float* bias  = (const float*)d_in[5];
    const float* h0    = (const float*)d_in[6];
    const float* mask  = (const float*)d_in[7];
    float* out = (float*)d_out;

    char* ws = (char*)d_ws;
    unsigned short* Wfh = (unsigned short*)(ws + 0);
    unsigned short* Wfl = (unsigned short*)(ws + 14254080);
    unsigned short* rSt = (unsigned short*)(ws + 28508160);   // 8 x 917504 B
    float* dsR = (float*)(ws + 35848192);                     // 8 x 1048576 B
    unsigned short* xh = (unsigned short*)(ws + 44236800);
    unsigned short* xl = (unsigned short*)(ws + 47513600);
    int*   bar  = (int*)(ws + 50790400);                      // 33792 B
    float* part = (float*)(ws + 50824192);                    // 32.77 MB

    hipLaunchKernelGGL(prep_w, dim3(15, 1856), dim3(256), 0, stream, w_rec, w_in, mask, Wfh, Wfl);
    hipLaunchKernelGGL(prep_x, dim3(6400), dim3(256), 0, stream, x, xh, xl);
    hipLaunchKernelGGL(init_state, dim3(15, B_SZ), dim3(256), 0, stream, h0, rSt, dsR);
    hipLaunchKernelGGL(zero_bar, dim3(1), dim3(1024), 0, stream, bar);

    void* params[] = {
        (void*)&Wfh, (void*)&Wfl, (void*)&rSt, (void*)&dsR,
        (void*)&xh, (void*)&xl, (void*)&noise, (void*)&bias, (void*)&w_out,
        (void*)&h0, (void*)&part, (void*)&bar
    };
    hipLaunchCooperativeKernel(rnn_persist, dim3(NTILES), dim3(1024), params, 0, stream);

    hipLaunchKernelGGL(reduce_out, dim3(T_STEPS), dim3(256), 0, stream, part, out);
}